// Round 2
// baseline (423.231 us; speedup 1.0000x reference)
//
#include <hip/hip_runtime.h>
#include <stdint.h>

#define BATCH 16
#define NQ 2000
#define NC 80
#define NG 100
#define MAX_ITERS 1000
#define BS 1024
#define NWAVE 16
#define MAXC 96

// output layout (floats)
#define OFF_SEL 0
#define OFF_GTI (BATCH * NQ)                 // 32000
#define OFF_MQ (2 * BATCH * NQ)              // 64000
#define OFF_M (2 * BATCH * NQ + BATCH * NG)  // 65600

// exact replay of the reference's sequential in-place adds
__device__ __forceinline__ float fmut(float c, int k) {
    for (int i = 0; i < k; ++i) c += 100000.0f;
    return c;
}

// ---------------- Kernel A1: fg_mask per (b,q) ----------------
__global__ void fg_kernel(const float* __restrict__ pred_boxes,
                          const float* __restrict__ gt_boxes,
                          const float* __restrict__ img_sz,
                          float* __restrict__ fg_out) {
    int idx = blockIdx.x * blockDim.x + threadIdx.x;
    if (idx >= BATCH * NQ) return;
    int b = idx / NQ, q = idx - b * NQ;
    const float* img = img_sz + b * 4;
    float i0 = img[0], i1 = img[1], i2 = img[2], i3 = img[3];
    const float* pb = pred_boxes + (b * NQ + q) * 4;
    float cx = pb[0], cy = pb[1], w = pb[2], h = pb[3];
    float x1 = (cx - 0.5f * w) * i0, y1 = (cy - 0.5f * h) * i1;
    float x2 = (cx + 0.5f * w) * i2, y2 = (cy + 0.5f * h) * i3;
    float ax = (x1 + x2) * 0.5f, ay = (y1 + y2) * 0.5f;
    bool fg = false;
    const float* gt = gt_boxes + b * NG * 4;
    for (int g = 0; g < NG; ++g) {
        float gcx = gt[g * 4 + 0], gcy = gt[g * 4 + 1], gw = gt[g * 4 + 2], gh = gt[g * 4 + 3];
        float GX1 = (gcx - 0.5f * gw) * i0, GY1 = (gcy - 0.5f * gh) * i1;
        float GX2 = (gcx + 0.5f * gw) * i2, GY2 = (gcy + 0.5f * gh) * i3;
        float tcx = (GX1 + GX2) * 0.5f, tcy = (GY1 + GY2) * 0.5f;
        float tw = GX2 - GX1, th = GY2 - GY1;
        float X1 = tcx - 0.5f * tw, Y1 = tcy - 0.5f * th;
        float X2 = tcx + 0.5f * tw, Y2 = tcy + 0.5f * th;
        bool in_box = (ax > X1) && (ax < X2) && (ay > Y1) && (ay < Y2);
        float w_ = X2 - X1, h_ = Y2 - Y1;
        bool in_ctr = (ax > tcx - 2.5f * w_) && (ax < tcx + 2.5f * w_) &&
                      (ay > tcy - 2.5f * h_) && (ay < tcy + 2.5f * h_);
        fg = fg || in_box || in_ctr;
    }
    fg_out[idx] = fg ? 1.0f : 0.0f;
}

// ---------------- Kernel A2: cost, TRANSPOSED output costT[b][g][q] ----------------
__global__ void cost_kernel(const float* __restrict__ logits,
                            const float* __restrict__ pred_boxes,
                            const float* __restrict__ gt_boxes,
                            const int* __restrict__ labels,
                            const float* __restrict__ img_sz,
                            const float* __restrict__ fg_in,
                            float* __restrict__ costT) {
    int idx = blockIdx.x * blockDim.x + threadIdx.x;
    if (idx >= BATCH * NQ * NG) return;
    int b = idx / (NQ * NG);
    int r = idx - b * (NQ * NG);
    int g = r / NQ;
    int q = r - g * NQ;

    const float* img = img_sz + b * 4;
    float i0 = img[0], i1 = img[1], i2 = img[2], i3 = img[3];

    const float* pb = pred_boxes + (b * NQ + q) * 4;
    float cx = pb[0], cy = pb[1], w = pb[2], h = pb[3];
    float x1 = (cx - 0.5f * w) * i0, y1 = (cy - 0.5f * h) * i1;
    float x2 = (cx + 0.5f * w) * i2, y2 = (cy + 0.5f * h) * i3;

    const float* gt = gt_boxes + (b * NG + g) * 4;
    float gcx = gt[0], gcy = gt[1], gw = gt[2], gh = gt[3];
    float GX1 = (gcx - 0.5f * gw) * i0, GY1 = (gcy - 0.5f * gh) * i1;
    float GX2 = (gcx + 0.5f * gw) * i2, GY2 = (gcy + 0.5f * gh) * i3;

    float ax = (x1 + x2) * 0.5f, ay = (y1 + y2) * 0.5f;
    float tcx = (GX1 + GX2) * 0.5f, tcy = (GY1 + GY2) * 0.5f;
    float tw = GX2 - GX1, th = GY2 - GY1;
    float X1 = tcx - 0.5f * tw, Y1 = tcy - 0.5f * th;
    float X2 = tcx + 0.5f * tw, Y2 = tcy + 0.5f * th;
    bool in_box = (ax > X1) && (ax < X2) && (ay > Y1) && (ay < Y2);
    float w_ = X2 - X1, h_ = Y2 - Y1;
    bool in_ctr = (ax > tcx - 2.5f * w_) && (ax < tcx + 2.5f * w_) &&
                  (ay > tcy - 2.5f * h_) && (ay < tcy + 2.5f * h_);
    bool in_bc = in_box && in_ctr;
    bool fgb = fg_in[b * NQ + q] != 0.0f;

    int lab = labels[b * NG + g];
    float lg = logits[(b * NQ + q) * NC + lab];
    float p = 1.0f / (1.0f + expf(-lg));
    float neg = 0.75f * (p * p) * (-logf(1.0f - p + 1e-8f));
    float pos = 0.25f * ((1.0f - p) * (1.0f - p)) * (-logf(p + 1e-8f));
    float cc = pos - neg;

    float cb = fabsf(x1 / i0 - GX1 / i0);
    cb = cb + fabsf(y1 / i1 - GY1 / i1);
    cb = cb + fabsf(x2 / i2 - GX2 / i2);
    cb = cb + fabsf(y2 / i3 - GY2 / i3);

    float aA = (x2 - x1) * (y2 - y1);
    float aB = (GX2 - GX1) * (GY2 - GY1);
    float lx = fmaxf(x1, GX1), ly = fmaxf(y1, GY1);
    float rx = fminf(x2, GX2), ry = fminf(y2, GY2);
    float iw = fmaxf(rx - lx, 0.0f), ih = fmaxf(ry - ly, 0.0f);
    float inter = iw * ih;
    float uni = aA + aB - inter;
    float iou = inter / uni;
    float hx1 = fminf(x1, GX1), hy1 = fminf(y1, GY1);
    float hx2 = fmaxf(x2, GX2), hy2 = fmaxf(y2, GY2);
    float hw = fmaxf(hx2 - hx1, 0.0f), hh = fmaxf(hy2 - hy1, 0.0f);
    float harea = hw * hh;
    float giou = iou - (harea - uni) / harea;

    float cost = 5.0f * cb;
    cost = cost + 2.0f * cc;
    cost = cost + 2.0f * (-giou);
    cost = cost + (in_bc ? 0.0f : 100.0f);
    cost = cost + (fgb ? 0.0f : 10000.0f);

    costT[idx] = cost;  // idx == b*(NG*NQ) + g*NQ + q
}

// ---------------- Kernel B: per-batch dynamic-k matching ----------------
#define SWAPVI(av, ai, bv, bi) { float tv_ = av; av = bv; bv = tv_; int ti_ = ai; ai = bi; bi = ti_; }
#define LEXLT(v, i, V, I) ((v) < (V) || ((v) == (V) && (i) < (I)))
#define INSB(vv, ii) do { float v_ = (vv); int i_ = (ii); \
    if (LEXLT(v_, i_, bv4, bi4)) { bv4 = v_; bi4 = i_; \
        if (LEXLT(bv4, bi4, bv3, bi3)) SWAPVI(bv3, bi3, bv4, bi4); \
        if (LEXLT(bv3, bi3, bv2, bi2)) SWAPVI(bv2, bi2, bv3, bi3); \
        if (LEXLT(bv2, bi2, bv1, bi1)) SWAPVI(bv1, bi1, bv2, bi2); \
        if (LEXLT(bv1, bi1, bv0, bi0)) SWAPVI(bv0, bi0, bv1, bi1); \
    } } while (0)
#define INST(vv) do { float v_ = (vv); \
    if (v_ > t4) { t4 = v_; \
        if (t4 > t3) { float x_ = t3; t3 = t4; t4 = x_; } \
        if (t3 > t2) { float x_ = t2; t2 = t3; t3 = x_; } \
        if (t2 > t1) { float x_ = t1; t1 = t2; t2 = x_; } \
        if (t1 > t0) { float x_ = t0; t0 = t1; t1 = x_; } \
    } } while (0)

__global__ __launch_bounds__(BS) void match_kernel(const float* __restrict__ pred_boxes,
                                                   const float* __restrict__ gt_boxes,
                                                   const float* __restrict__ img_sz,
                                                   float* __restrict__ out) {
    const int b = blockIdx.x;
    const int tid = threadIdx.x;
    const int wave = tid >> 6;
    const int lane = tid & 63;

    __shared__ uint32_t Msh[NQ][4];       // 32 KB  row bitmasks
    __shared__ float crow[MAXC][NG];      // 38.4 KB cached mutated conflict0 rows
    __shared__ int n_q[NQ];               // 8 KB   penalty counts
    __shared__ int16_t cidx[NQ];          // 4 KB   row -> cache slot (-1 none, -2 conf0-uncached)
    __shared__ uint8_t conf0[NQ];         // 2 KB
    __shared__ uint8_t slotM[MAXC];       // matched flag per cached row (this iter)
    __shared__ int crowq[MAXC];
    __shared__ float gx1s[NG], gy1s[NG], gx2s[NG], gy2s[NG], gAs[NG];
    __shared__ int colcnt[NG], dynk[NG];
    __shared__ float imgs[4];
    __shared__ int flags[2];              // [0]=any unmatched col, [1]=has_conf
    __shared__ int nconf0;

    float* costT = out + OFF_M + (size_t)b * NQ * NG;  // transposed cost; later M output
    float* selOut = out + OFF_SEL + b * NQ;
    float* gtiOut = out + OFF_GTI + b * NQ;
    float* mqOut = out + OFF_MQ + b * NG;

    if (tid < 4) imgs[tid] = img_sz[b * 4 + tid];
    if (tid == 0) { flags[0] = 0; flags[1] = 0; nconf0 = 0; }
    for (int q = tid; q < NQ; q += BS) {
        Msh[q][0] = 0; Msh[q][1] = 0; Msh[q][2] = 0; Msh[q][3] = 0;
        conf0[q] = 0; cidx[q] = -1; n_q[q] = 0;
    }
    __syncthreads();
    const float i0 = imgs[0], i1 = imgs[1], i2 = imgs[2], i3 = imgs[3];
    if (tid < NG) {
        const float* gt = gt_boxes + (b * NG + tid) * 4;
        float gcx = gt[0], gcy = gt[1], gw = gt[2], gh = gt[3];
        float X1 = (gcx - 0.5f * gw) * i0, Y1 = (gcy - 0.5f * gh) * i1;
        float X2 = (gcx + 0.5f * gw) * i2, Y2 = (gcy + 0.5f * gh) * i3;
        gx1s[tid] = X1; gy1s[tid] = Y1; gx2s[tid] = X2; gy2s[tid] = Y2;
        gAs[tid] = (X2 - X1) * (Y2 - Y1);
        colcnt[tid] = 0;
    }
    __syncthreads();

    const float* pbox = pred_boxes + (size_t)b * NQ * 4;

    // Phase 1: dyn_k = clip(int(sum top5 IoU per gt), 1)
    for (int g = wave; g < NG; g += NWAVE) {
        float t0 = -INFINITY, t1 = -INFINITY, t2 = -INFINITY, t3 = -INFINITY, t4 = -INFINITY;
        float GX1 = gx1s[g], GY1 = gy1s[g], GX2 = gx2s[g], GY2 = gy2s[g], GA = gAs[g];
        for (int q = lane; q < NQ; q += 64) {
            const float4 pb = *reinterpret_cast<const float4*>(pbox + q * 4);
            float x1 = (pb.x - 0.5f * pb.z) * i0, y1 = (pb.y - 0.5f * pb.w) * i1;
            float x2 = (pb.x + 0.5f * pb.z) * i2, y2 = (pb.y + 0.5f * pb.w) * i3;
            float aA = (x2 - x1) * (y2 - y1);
            float lx = fmaxf(x1, GX1), ly = fmaxf(y1, GY1);
            float rx = fminf(x2, GX2), ry = fminf(y2, GY2);
            float iw = fmaxf(rx - lx, 0.0f), ih = fmaxf(ry - ly, 0.0f);
            float inter = iw * ih;
            float uni = aA + GA - inter;
            float iou = inter / uni;
            INST(iou);
        }
        for (int off = 1; off < 64; off <<= 1) {
            float o0 = __shfl_xor(t0, off), o1 = __shfl_xor(t1, off), o2 = __shfl_xor(t2, off);
            float o3 = __shfl_xor(t3, off), o4 = __shfl_xor(t4, off);
            INST(o0); INST(o1); INST(o2); INST(o3); INST(o4);
        }
        if (lane == 0) {
            float s = t0 + t1 + t2 + t3 + t4;
            int k = (int)s;
            if (k < 1) k = 1;
            dynk[g] = k;
        }
    }
    __syncthreads();

    // Phase 2: initial M = bottom-dyn_k costs per column (contiguous reads via costT)
    for (int g = wave; g < NG; g += NWAVE) {
        const float* col = costT + (size_t)g * NQ;
        float bv0 = INFINITY, bv1 = INFINITY, bv2 = INFINITY, bv3 = INFINITY, bv4 = INFINITY;
        int bi0 = 0x7fffffff, bi1 = 0x7fffffff, bi2 = 0x7fffffff, bi3 = 0x7fffffff, bi4 = 0x7fffffff;
        for (int q = lane; q < NQ; q += 64) {
            float v = col[q];
            INSB(v, q);
        }
        for (int off = 1; off < 64; off <<= 1) {
            float ov0 = __shfl_xor(bv0, off); int oi0 = __shfl_xor(bi0, off);
            float ov1 = __shfl_xor(bv1, off); int oi1 = __shfl_xor(bi1, off);
            float ov2 = __shfl_xor(bv2, off); int oi2 = __shfl_xor(bi2, off);
            float ov3 = __shfl_xor(bv3, off); int oi3 = __shfl_xor(bi3, off);
            float ov4 = __shfl_xor(bv4, off); int oi4 = __shfl_xor(bi4, off);
            INSB(ov0, oi0); INSB(ov1, oi1); INSB(ov2, oi2); INSB(ov3, oi3); INSB(ov4, oi4);
        }
        if (lane == 0) {
            int k = dynk[g];
            int word = g >> 5;
            uint32_t bit = 1u << (g & 31);
            atomicOr(&Msh[bi0][word], bit);
            if (k > 1) atomicOr(&Msh[bi1][word], bit);
            if (k > 2) atomicOr(&Msh[bi2][word], bit);
            if (k > 3) atomicOr(&Msh[bi3][word], bit);
            if (k > 4) atomicOr(&Msh[bi4][word], bit);
            colcnt[g] = k;
        }
    }
    __syncthreads();

    // Phase 3: conflict0 rows -> onehot(row argmin of original cost); cache their rows
    for (int q = tid; q < NQ; q += BS) {
        int pc = __popc(Msh[q][0]) + __popc(Msh[q][1]) + __popc(Msh[q][2]) + __popc(Msh[q][3]);
        if (pc > 1) {
            conf0[q] = 1;
            int slot = atomicAdd(&nconf0, 1);
            int c = (slot < MAXC) ? slot : -1;
            cidx[q] = (c >= 0) ? (int16_t)c : (int16_t)-2;
            if (c >= 0) crowq[c] = q;
            float mv = INFINITY; int mg = 0;
            for (int g = 0; g < NG; ++g) {
                float v = costT[(size_t)g * NQ + q];
                if (c >= 0) crow[c][g] = v;
                if (v < mv) { mv = v; mg = g; }
            }
            for (int w = 0; w < 4; ++w) {
                uint32_t word = Msh[q][w];
                while (word) {
                    int bp = __ffs(word) - 1;
                    word &= word - 1;
                    atomicSub(&colcnt[w * 32 + bp], 1);
                }
                Msh[q][w] = 0;
            }
            Msh[q][mg >> 5] = 1u << (mg & 31);
            atomicAdd(&colcnt[mg], 1);
        }
    }
    __syncthreads();
    // initial loop condition
    if (tid < NG && colcnt[tid] == 0) flags[0] = 1;
    __syncthreads();

    const int ncached = (nconf0 < MAXC) ? nconf0 : MAXC;

    // ---------------- while loop ----------------
    for (int it = 0; it < MAX_ITERS; ++it) {
        if (!flags[0]) break;

        // P1: matched-at-entry -> n_q++, mark cached rows
        for (int q = tid; q < NQ; q += BS) {
            bool m = (Msh[q][0] | Msh[q][1] | Msh[q][2] | Msh[q][3]) != 0;
            if (m) n_q[q]++;
            int c = cidx[q];
            if (c >= 0) slotM[c] = m ? 1 : 0;
        }
        __syncthreads();  // B1

        // P1b: apply +1e5 to cached matched rows (exact replay of ref mutation)
        for (int i = tid; i < ncached * NG; i += BS) {
            int s = i / NG, g = i - s * NG;
            if (slotM[s]) crow[s][g] += 100000.0f;
        }
        // P2: unmatched columns pick argmin among n==0 rows of ORIGINAL cost
        for (int g = wave; g < NG; g += NWAVE) {
            if (colcnt[g] != 0) continue;
            const float* col = costT + (size_t)g * NQ;
            float mv = INFINITY; int mi = 0x7fffffff;
            for (int q = lane; q < NQ; q += 64) {
                if (n_q[q] == 0) {
                    float v = col[q];
                    if (v < mv || (v == mv && q < mi)) { mv = v; mi = q; }
                }
            }
            for (int off = 1; off < 64; off <<= 1) {
                float ov = __shfl_xor(mv, off); int oi = __shfl_xor(mi, off);
                if (ov < mv || (ov == mv && oi < mi)) { mv = ov; mi = oi; }
            }
            if (mi == 0x7fffffff) {  // fallback: every row penalized -> exact replay
                for (int q = lane; q < NQ; q += 64) {
                    float v = fmut(col[q], n_q[q]);
                    if (v < mv || (v == mv && q < mi)) { mv = v; mi = q; }
                }
                for (int off = 1; off < 64; off <<= 1) {
                    float ov = __shfl_xor(mv, off); int oi = __shfl_xor(mi, off);
                    if (ov < mv || (ov == mv && oi < mi)) { mv = ov; mi = oi; }
                }
            }
            if (lane == 0) {
                atomicOr(&Msh[mi][g >> 5], 1u << (g & 31));
                colcnt[g] = 1;
            }
        }
        __syncthreads();  // B2

        // P3: has_conf = any row popcount > 1 (LDS scan); pre-reset flags[0]
        if (tid == 0) flags[0] = 0;
        for (int q = tid; q < NQ; q += BS) {
            int pc = __popc(Msh[q][0]) + __popc(Msh[q][1]) + __popc(Msh[q][2]) + __popc(Msh[q][3]);
            if (pc > 1) flags[1] = 1;
        }
        __syncthreads();  // B3

        // P4: if has_conf, reset ALL conflict0 rows to onehot(argmin of mutated row)
        if (flags[1]) {
            for (int q = tid; q < NQ; q += BS) {
                if (!conf0[q]) continue;
                int c = cidx[q];
                float mv; int mg = 0;
                if (c >= 0) {
                    mv = crow[c][0];
                    for (int g = 1; g < NG; ++g) { float v = crow[c][g]; if (v < mv) { mv = v; mg = g; } }
                } else {
                    int k = n_q[q];
                    mv = fmut(costT[q], k);
                    for (int g = 1; g < NG; ++g) {
                        float v = fmut(costT[(size_t)g * NQ + q], k);
                        if (v < mv) { mv = v; mg = g; }
                    }
                }
                int keepw = mg >> 5;
                uint32_t keepb = 1u << (mg & 31);
                for (int w = 0; w < 4; ++w) {
                    uint32_t word = Msh[q][w];
                    uint32_t keep = (w == keepw) ? keepb : 0u;
                    uint32_t toclear = word & ~keep;
                    while (toclear) {
                        int bp = __ffs(toclear) - 1;
                        toclear &= toclear - 1;
                        atomicSub(&colcnt[w * 32 + bp], 1);
                    }
                    if (keep && !(word & keep)) atomicAdd(&colcnt[mg], 1);
                    Msh[q][w] = keep;
                }
            }
        }
        __syncthreads();  // B4

        // P5: recompute loop condition; reset has_conf
        if (tid < NG && colcnt[tid] == 0) flags[0] = 1;
        if (tid == 0) flags[1] = 0;
        __syncthreads();  // B5
    }

    // matched_qid: argmin_q of (M ? mutated cost : 1e30), exact mutated values
    for (int g = wave; g < NG; g += NWAVE) {
        int word = g >> 5;
        uint32_t bit = 1u << (g & 31);
        const float* col = costT + (size_t)g * NQ;
        float mv = INFINITY; int mi = 0x7fffffff;
        for (int q = lane; q < NQ; q += 64) {
            float v = 1e30f;
            if (Msh[q][word] & bit) {
                int c = cidx[q];
                v = (c >= 0) ? crow[c][g] : fmut(col[q], n_q[q]);
            }
            if (v < mv || (v == mv && q < mi)) { mv = v; mi = q; }
        }
        for (int off = 1; off < 64; off <<= 1) {
            float ov = __shfl_xor(mv, off); int oi = __shfl_xor(mi, off);
            if (ov < mv || (ov == mv && oi < mi)) { mv = ov; mi = oi; }
        }
        if (lane == 0) mqOut[g] = (float)mi;
    }
    // selected / gt_idx
    for (int q = tid; q < NQ; q += BS) {
        uint32_t w0 = Msh[q][0], w1 = Msh[q][1], w2 = Msh[q][2], w3 = Msh[q][3];
        selOut[q] = (w0 | w1 | w2 | w3) ? 1.0f : 0.0f;
        int gi = 0;
        if (w0) gi = __ffs(w0) - 1;
        else if (w1) gi = 32 + __ffs(w1) - 1;
        else if (w2) gi = 64 + __ffs(w2) - 1;
        else if (w3) gi = 96 + __ffs(w3) - 1;
        gtiOut[q] = (float)gi;
    }
    __syncthreads();  // all costT reads done before overwriting with M
    // M output (row-major q,g) overwrites costT buffer
    for (int i = tid; i < NQ * NG; i += BS) {
        int q = i / NG;
        int g = i - q * NG;
        costT[i] = (Msh[q][g >> 5] & (1u << (g & 31))) ? 1.0f : 0.0f;
    }
}

extern "C" void kernel_launch(void* const* d_in, const int* in_sizes, int n_in,
                              void* d_out, int out_size, void* d_ws, size_t ws_size,
                              hipStream_t stream) {
    const float* logits = (const float*)d_in[0];
    const float* pboxes = (const float*)d_in[1];
    const float* gboxes = (const float*)d_in[2];
    const int* labels = (const int*)d_in[3];
    const float* img = (const float*)d_in[4];
    float* out = (float*)d_out;

    fg_kernel<<<(BATCH * NQ + 255) / 256, 256, 0, stream>>>(pboxes, gboxes, img, out + OFF_SEL);
    cost_kernel<<<(BATCH * NQ * NG + 255) / 256, 256, 0, stream>>>(
        logits, pboxes, gboxes, labels, img, out + OFF_SEL, out + OFF_M);
    match_kernel<<<BATCH, BS, 0, stream>>>(pboxes, gboxes, img, out);
}

// Round 3
// 193.546 us; speedup vs baseline: 2.1867x; 2.1867x over previous
//
#include <hip/hip_runtime.h>
#include <stdint.h>

#define BATCH 16
#define NQ 2000
#define NC 80
#define NG 100
#define MAX_ITERS 1000
#define BS 1024
#define NWAVE 16
#define MAXC 96

// output layout (floats)
#define OFF_SEL 0
#define OFF_GTI (BATCH * NQ)                 // 32000
#define OFF_MQ (2 * BATCH * NQ)              // 64000
#define OFF_M (2 * BATCH * NQ + BATCH * NG)  // 65600

// exact replay of the reference's sequential in-place adds
__device__ __forceinline__ float fmut(float c, int k) {
    for (int i = 0; i < k; ++i) c += 100000.0f;
    return c;
}

#define SWAPVI(av, ai, bv, bi) { float tv_ = av; av = bv; bv = tv_; int ti_ = ai; ai = bi; bi = ti_; }
#define LEXLT(v, i, V, I) ((v) < (V) || ((v) == (V) && (i) < (I)))
#define INSB(vv, ii) do { float v_ = (vv); int i_ = (ii); \
    if (LEXLT(v_, i_, bv4, bi4)) { bv4 = v_; bi4 = i_; \
        if (LEXLT(bv4, bi4, bv3, bi3)) SWAPVI(bv3, bi3, bv4, bi4); \
        if (LEXLT(bv3, bi3, bv2, bi2)) SWAPVI(bv2, bi2, bv3, bi3); \
        if (LEXLT(bv2, bi2, bv1, bi1)) SWAPVI(bv1, bi1, bv2, bi2); \
        if (LEXLT(bv1, bi1, bv0, bi0)) SWAPVI(bv0, bi0, bv1, bi1); \
    } } while (0)
#define INST(vv) do { float v_ = (vv); \
    if (v_ > t4) { t4 = v_; \
        if (t4 > t3) { float x_ = t3; t3 = t4; t4 = x_; } \
        if (t3 > t2) { float x_ = t2; t2 = t3; t3 = x_; } \
        if (t2 > t1) { float x_ = t1; t1 = t2; t2 = x_; } \
        if (t1 > t0) { float x_ = t0; t0 = t1; t1 = x_; } \
    } } while (0)

// ---------------- Kernel A1: fg_mask per (b,q) ----------------
__global__ void fg_kernel(const float* __restrict__ pred_boxes,
                          const float* __restrict__ gt_boxes,
                          const float* __restrict__ img_sz,
                          float* __restrict__ fg_out) {
    int idx = blockIdx.x * blockDim.x + threadIdx.x;
    if (idx >= BATCH * NQ) return;
    int b = idx / NQ, q = idx - b * NQ;
    const float* img = img_sz + b * 4;
    float i0 = img[0], i1 = img[1], i2 = img[2], i3 = img[3];
    const float* pb = pred_boxes + (b * NQ + q) * 4;
    float cx = pb[0], cy = pb[1], w = pb[2], h = pb[3];
    float x1 = (cx - 0.5f * w) * i0, y1 = (cy - 0.5f * h) * i1;
    float x2 = (cx + 0.5f * w) * i2, y2 = (cy + 0.5f * h) * i3;
    float ax = (x1 + x2) * 0.5f, ay = (y1 + y2) * 0.5f;
    bool fg = false;
    const float* gt = gt_boxes + b * NG * 4;
    for (int g = 0; g < NG; ++g) {
        float gcx = gt[g * 4 + 0], gcy = gt[g * 4 + 1], gw = gt[g * 4 + 2], gh = gt[g * 4 + 3];
        float GX1 = (gcx - 0.5f * gw) * i0, GY1 = (gcy - 0.5f * gh) * i1;
        float GX2 = (gcx + 0.5f * gw) * i2, GY2 = (gcy + 0.5f * gh) * i3;
        float tcx = (GX1 + GX2) * 0.5f, tcy = (GY1 + GY2) * 0.5f;
        float tw = GX2 - GX1, th = GY2 - GY1;
        float X1 = tcx - 0.5f * tw, Y1 = tcy - 0.5f * th;
        float X2 = tcx + 0.5f * tw, Y2 = tcy + 0.5f * th;
        bool in_box = (ax > X1) && (ax < X2) && (ay > Y1) && (ay < Y2);
        float w_ = X2 - X1, h_ = Y2 - Y1;
        bool in_ctr = (ax > tcx - 2.5f * w_) && (ax < tcx + 2.5f * w_) &&
                      (ay > tcy - 2.5f * h_) && (ay < tcy + 2.5f * h_);
        fg = fg || in_box || in_ctr;
    }
    fg_out[idx] = fg ? 1.0f : 0.0f;
}

// ---------------- Kernel A2: cost, TRANSPOSED output costT[b][g][q] ----------------
__global__ void cost_kernel(const float* __restrict__ logits,
                            const float* __restrict__ pred_boxes,
                            const float* __restrict__ gt_boxes,
                            const int* __restrict__ labels,
                            const float* __restrict__ img_sz,
                            const float* __restrict__ fg_in,
                            float* __restrict__ costT) {
    int idx = blockIdx.x * blockDim.x + threadIdx.x;
    if (idx >= BATCH * NQ * NG) return;
    int b = idx / (NQ * NG);
    int r = idx - b * (NQ * NG);
    int g = r / NQ;
    int q = r - g * NQ;

    const float* img = img_sz + b * 4;
    float i0 = img[0], i1 = img[1], i2 = img[2], i3 = img[3];

    const float* pb = pred_boxes + (b * NQ + q) * 4;
    float cx = pb[0], cy = pb[1], w = pb[2], h = pb[3];
    float x1 = (cx - 0.5f * w) * i0, y1 = (cy - 0.5f * h) * i1;
    float x2 = (cx + 0.5f * w) * i2, y2 = (cy + 0.5f * h) * i3;

    const float* gt = gt_boxes + (b * NG + g) * 4;
    float gcx = gt[0], gcy = gt[1], gw = gt[2], gh = gt[3];
    float GX1 = (gcx - 0.5f * gw) * i0, GY1 = (gcy - 0.5f * gh) * i1;
    float GX2 = (gcx + 0.5f * gw) * i2, GY2 = (gcy + 0.5f * gh) * i3;

    float ax = (x1 + x2) * 0.5f, ay = (y1 + y2) * 0.5f;
    float tcx = (GX1 + GX2) * 0.5f, tcy = (GY1 + GY2) * 0.5f;
    float tw = GX2 - GX1, th = GY2 - GY1;
    float X1 = tcx - 0.5f * tw, Y1 = tcy - 0.5f * th;
    float X2 = tcx + 0.5f * tw, Y2 = tcy + 0.5f * th;
    bool in_box = (ax > X1) && (ax < X2) && (ay > Y1) && (ay < Y2);
    float w_ = X2 - X1, h_ = Y2 - Y1;
    bool in_ctr = (ax > tcx - 2.5f * w_) && (ax < tcx + 2.5f * w_) &&
                  (ay > tcy - 2.5f * h_) && (ay < tcy + 2.5f * h_);
    bool in_bc = in_box && in_ctr;
    bool fgb = fg_in[b * NQ + q] != 0.0f;

    int lab = labels[b * NG + g];
    float lg = logits[(b * NQ + q) * NC + lab];
    float p = 1.0f / (1.0f + expf(-lg));
    float neg = 0.75f * (p * p) * (-logf(1.0f - p + 1e-8f));
    float pos = 0.25f * ((1.0f - p) * (1.0f - p)) * (-logf(p + 1e-8f));
    float cc = pos - neg;

    float cb = fabsf(x1 / i0 - GX1 / i0);
    cb = cb + fabsf(y1 / i1 - GY1 / i1);
    cb = cb + fabsf(x2 / i2 - GX2 / i2);
    cb = cb + fabsf(y2 / i3 - GY2 / i3);

    float aA = (x2 - x1) * (y2 - y1);
    float aB = (GX2 - GX1) * (GY2 - GY1);
    float lx = fmaxf(x1, GX1), ly = fmaxf(y1, GY1);
    float rx = fminf(x2, GX2), ry = fminf(y2, GY2);
    float iw = fmaxf(rx - lx, 0.0f), ih = fmaxf(ry - ly, 0.0f);
    float inter = iw * ih;
    float uni = aA + aB - inter;
    float iou = inter / uni;
    float hx1 = fminf(x1, GX1), hy1 = fminf(y1, GY1);
    float hx2 = fmaxf(x2, GX2), hy2 = fmaxf(y2, GY2);
    float hw = fmaxf(hx2 - hx1, 0.0f), hh = fmaxf(hy2 - hy1, 0.0f);
    float harea = hw * hh;
    float giou = iou - (harea - uni) / harea;

    float cost = 5.0f * cb;
    cost = cost + 2.0f * cc;
    cost = cost + 2.0f * (-giou);
    cost = cost + (in_bc ? 0.0f : 100.0f);
    cost = cost + (fgb ? 0.0f : 10000.0f);

    costT[idx] = cost;  // idx == b*(NG*NQ) + g*NQ + q
}

// ---------------- Kernel A3: one wave per (b,g): dyn_k + bottom-5 cost ----------------
__global__ __launch_bounds__(256) void dynk_init_kernel(const float* __restrict__ pred_boxes,
                                                        const float* __restrict__ gt_boxes,
                                                        const float* __restrict__ img_sz,
                                                        const float* __restrict__ costT_all,
                                                        float* __restrict__ lists) {
    int waveg = blockIdx.x * 4 + (threadIdx.x >> 6);
    int lane = threadIdx.x & 63;
    int b = waveg / NG, g = waveg - b * NG;

    const float* img = img_sz + b * 4;
    float i0 = img[0], i1 = img[1], i2 = img[2], i3 = img[3];
    const float* gt = gt_boxes + (b * NG + g) * 4;
    float gcx = gt[0], gcy = gt[1], gw = gt[2], gh = gt[3];
    float GX1 = (gcx - 0.5f * gw) * i0, GY1 = (gcy - 0.5f * gh) * i1;
    float GX2 = (gcx + 0.5f * gw) * i2, GY2 = (gcy + 0.5f * gh) * i3;
    float GA = (GX2 - GX1) * (GY2 - GY1);

    // top-5 IoU over q
    const float* pbox = pred_boxes + (size_t)b * NQ * 4;
    float t0 = -INFINITY, t1 = -INFINITY, t2 = -INFINITY, t3 = -INFINITY, t4 = -INFINITY;
    for (int q = lane; q < NQ; q += 64) {
        const float4 pb = *reinterpret_cast<const float4*>(pbox + q * 4);
        float x1 = (pb.x - 0.5f * pb.z) * i0, y1 = (pb.y - 0.5f * pb.w) * i1;
        float x2 = (pb.x + 0.5f * pb.z) * i2, y2 = (pb.y + 0.5f * pb.w) * i3;
        float aA = (x2 - x1) * (y2 - y1);
        float lx = fmaxf(x1, GX1), ly = fmaxf(y1, GY1);
        float rx = fminf(x2, GX2), ry = fminf(y2, GY2);
        float iw = fmaxf(rx - lx, 0.0f), ih = fmaxf(ry - ly, 0.0f);
        float inter = iw * ih;
        float uni = aA + GA - inter;
        float iou = inter / uni;
        INST(iou);
    }
    for (int off = 1; off < 64; off <<= 1) {
        float o0 = __shfl_xor(t0, off), o1 = __shfl_xor(t1, off), o2 = __shfl_xor(t2, off);
        float o3 = __shfl_xor(t3, off), o4 = __shfl_xor(t4, off);
        INST(o0); INST(o1); INST(o2); INST(o3); INST(o4);
    }

    // bottom-5 cost over the (contiguous) column
    const float* col = costT_all + (size_t)b * NQ * NG + (size_t)g * NQ;
    float bv0 = INFINITY, bv1 = INFINITY, bv2 = INFINITY, bv3 = INFINITY, bv4 = INFINITY;
    int bi0 = 0x7fffffff, bi1 = 0x7fffffff, bi2 = 0x7fffffff, bi3 = 0x7fffffff, bi4 = 0x7fffffff;
    for (int q = lane; q < NQ; q += 64) {
        float v = col[q];
        INSB(v, q);
    }
    for (int off = 1; off < 64; off <<= 1) {
        float ov0 = __shfl_xor(bv0, off); int oi0 = __shfl_xor(bi0, off);
        float ov1 = __shfl_xor(bv1, off); int oi1 = __shfl_xor(bi1, off);
        float ov2 = __shfl_xor(bv2, off); int oi2 = __shfl_xor(bi2, off);
        float ov3 = __shfl_xor(bv3, off); int oi3 = __shfl_xor(bi3, off);
        float ov4 = __shfl_xor(bv4, off); int oi4 = __shfl_xor(bi4, off);
        INSB(ov0, oi0); INSB(ov1, oi1); INSB(ov2, oi2); INSB(ov3, oi3); INSB(ov4, oi4);
    }

    if (lane == 0) {
        float s = t0 + t1 + t2 + t3 + t4;
        int k = (int)s;
        if (k < 1) k = 1;
        float* o = lists + (size_t)(b * NG + g) * 6;
        o[0] = (float)k;
        o[1] = (float)bi0; o[2] = (float)bi1; o[3] = (float)bi2; o[4] = (float)bi3; o[5] = (float)bi4;
    }
}

// ---------------- Kernel A4: per-row argmin_g of original cost ----------------
__global__ void rowargmin_kernel(const float* __restrict__ costT_all,
                                 float* __restrict__ rowamin) {
    int idx = blockIdx.x * blockDim.x + threadIdx.x;
    if (idx >= BATCH * NQ) return;
    int b = idx / NQ, q = idx - b * NQ;
    const float* base = costT_all + (size_t)b * NQ * NG + q;
    float mv = base[0]; int mg = 0;
    for (int g = 1; g < NG; ++g) {
        float v = base[(size_t)g * NQ];
        if (v < mv) { mv = v; mg = g; }
    }
    rowamin[idx] = (float)mg;
}

// ---------------- Kernel B: per-batch dynamic-k matching ----------------
__global__ __launch_bounds__(BS) void match_kernel(const float* __restrict__ lists,
                                                   float* __restrict__ out) {
    const int b = blockIdx.x;
    const int tid = threadIdx.x;
    const int wave = tid >> 6;
    const int lane = tid & 63;

    __shared__ uint32_t Msh[NQ][4];       // 32 KB  row bitmasks
    __shared__ float crow[MAXC][NG];      // 38.4 KB cached mutated conflict0 rows
    __shared__ int n_q[NQ];               // 8 KB   penalty counts
    __shared__ int16_t cidx[NQ];          // 4 KB   row -> cache slot (-1 none, -2 conf0-uncached)
    __shared__ uint8_t conf0[NQ];         // 2 KB
    __shared__ uint8_t slotM[MAXC];       // matched flag per cached row (this iter)
    __shared__ int crowq[MAXC];
    __shared__ int colcnt[NG];
    __shared__ int flags[2];              // [0]=any unmatched col, [1]=has_conf
    __shared__ int nconf0;

    float* costT = out + OFF_M + (size_t)b * NQ * NG;  // transposed cost; later M output
    float* selOut = out + OFF_SEL + b * NQ;
    float* gtiOut = out + OFF_GTI + b * NQ;
    const float* rowamin_b = out + OFF_GTI + b * NQ;   // read in phase 3 before gtiOut write
    float* mqOut = out + OFF_MQ + b * NG;

    if (tid == 0) { flags[0] = 0; flags[1] = 0; nconf0 = 0; }
    for (int q = tid; q < NQ; q += BS) {
        Msh[q][0] = 0; Msh[q][1] = 0; Msh[q][2] = 0; Msh[q][3] = 0;
        conf0[q] = 0; cidx[q] = -1; n_q[q] = 0;
    }
    __syncthreads();

    // Build M + colcnt from precomputed lists
    if (tid < NG) {
        const float* o = lists + (size_t)(b * NG + tid) * 6;
        int k = (int)o[0];
        int word = tid >> 5;
        uint32_t bit = 1u << (tid & 31);
        atomicOr(&Msh[(int)o[1]][word], bit);
        if (k > 1) atomicOr(&Msh[(int)o[2]][word], bit);
        if (k > 2) atomicOr(&Msh[(int)o[3]][word], bit);
        if (k > 3) atomicOr(&Msh[(int)o[4]][word], bit);
        if (k > 4) atomicOr(&Msh[(int)o[5]][word], bit);
        colcnt[tid] = k;
    }
    __syncthreads();

    // Phase 3: conflict0 rows -> onehot(precomputed row argmin); assign cache slots
    for (int q = tid; q < NQ; q += BS) {
        uint4 m = *reinterpret_cast<const uint4*>(&Msh[q][0]);
        int pc = __popc(m.x) + __popc(m.y) + __popc(m.z) + __popc(m.w);
        if (pc > 1) {
            conf0[q] = 1;
            int slot = atomicAdd(&nconf0, 1);
            int c = (slot < MAXC) ? slot : -1;
            cidx[q] = (c >= 0) ? (int16_t)c : (int16_t)-2;
            if (c >= 0) crowq[c] = q;
            int mg = (int)rowamin_b[q];
            uint32_t words[4] = {m.x, m.y, m.z, m.w};
            for (int w = 0; w < 4; ++w) {
                uint32_t word = words[w];
                while (word) {
                    int bp = __ffs(word) - 1;
                    word &= word - 1;
                    atomicSub(&colcnt[w * 32 + bp], 1);
                }
                Msh[q][w] = 0;
            }
            Msh[q][mg >> 5] = 1u << (mg & 31);
            atomicAdd(&colcnt[mg], 1);
        }
    }
    __syncthreads();

    const int ncached = (nconf0 < MAXC) ? nconf0 : MAXC;
    // parallel crow fill (original cost; mutation replayed in-loop)
    for (int i = tid; i < ncached * NG; i += BS) {
        int c = i / NG, g = i - c * NG;
        crow[c][g] = costT[(size_t)g * NQ + crowq[c]];
    }
    // initial loop condition
    if (tid < NG && colcnt[tid] == 0) flags[0] = 1;
    __syncthreads();

    // ---------------- while loop ----------------
    for (int it = 0; it < MAX_ITERS; ++it) {
        if (!flags[0]) break;

        // P1: matched-at-entry -> n_q++, mark cached rows
        for (int q = tid; q < NQ; q += BS) {
            uint4 m = *reinterpret_cast<const uint4*>(&Msh[q][0]);
            bool mm = (m.x | m.y | m.z | m.w) != 0;
            if (mm) n_q[q]++;
            int c = cidx[q];
            if (c >= 0) slotM[c] = mm ? 1 : 0;
        }
        __syncthreads();  // B1

        // P1b: apply +1e5 to cached matched rows (exact replay of ref mutation)
        for (int i = tid; i < ncached * NG; i += BS) {
            int s = i / NG, g = i - s * NG;
            if (slotM[s]) crow[s][g] += 100000.0f;
        }
        // P2: unmatched columns pick argmin among n==0 rows of ORIGINAL cost
        for (int g = wave; g < NG; g += NWAVE) {
            if (colcnt[g] != 0) continue;
            const float* col = costT + (size_t)g * NQ;
            float mv = INFINITY; int mi = 0x7fffffff;
            for (int q = lane; q < NQ; q += 64) {
                if (n_q[q] == 0) {
                    float v = col[q];
                    if (v < mv || (v == mv && q < mi)) { mv = v; mi = q; }
                }
            }
            for (int off = 1; off < 64; off <<= 1) {
                float ov = __shfl_xor(mv, off); int oi = __shfl_xor(mi, off);
                if (ov < mv || (ov == mv && oi < mi)) { mv = ov; mi = oi; }
            }
            if (mi == 0x7fffffff) {  // fallback: every row penalized -> exact replay
                for (int q = lane; q < NQ; q += 64) {
                    float v = fmut(col[q], n_q[q]);
                    if (v < mv || (v == mv && q < mi)) { mv = v; mi = q; }
                }
                for (int off = 1; off < 64; off <<= 1) {
                    float ov = __shfl_xor(mv, off); int oi = __shfl_xor(mi, off);
                    if (ov < mv || (ov == mv && oi < mi)) { mv = ov; mi = oi; }
                }
            }
            if (lane == 0) {
                atomicOr(&Msh[mi][g >> 5], 1u << (g & 31));
                colcnt[g] = 1;
            }
        }
        __syncthreads();  // B2

        // P3: has_conf = any row popcount > 1; pre-reset flags[0]
        if (tid == 0) flags[0] = 0;
        for (int q = tid; q < NQ; q += BS) {
            uint4 m = *reinterpret_cast<const uint4*>(&Msh[q][0]);
            int pc = __popc(m.x) + __popc(m.y) + __popc(m.z) + __popc(m.w);
            if (pc > 1) flags[1] = 1;
        }
        __syncthreads();  // B3

        // P4: if has_conf, reset ALL conflict0 rows to onehot(argmin of mutated row)
        if (flags[1]) {
            for (int q = tid; q < NQ; q += BS) {
                if (!conf0[q]) continue;
                int c = cidx[q];
                float mv; int mg = 0;
                if (c >= 0) {
                    mv = crow[c][0];
                    for (int g = 1; g < NG; ++g) { float v = crow[c][g]; if (v < mv) { mv = v; mg = g; } }
                } else {
                    int k = n_q[q];
                    mv = fmut(costT[q], k);
                    for (int g = 1; g < NG; ++g) {
                        float v = fmut(costT[(size_t)g * NQ + q], k);
                        if (v < mv) { mv = v; mg = g; }
                    }
                }
                int keepw = mg >> 5;
                uint32_t keepb = 1u << (mg & 31);
                for (int w = 0; w < 4; ++w) {
                    uint32_t word = Msh[q][w];
                    uint32_t keep = (w == keepw) ? keepb : 0u;
                    uint32_t toclear = word & ~keep;
                    while (toclear) {
                        int bp = __ffs(toclear) - 1;
                        toclear &= toclear - 1;
                        atomicSub(&colcnt[w * 32 + bp], 1);
                    }
                    if (keep && !(word & keep)) atomicAdd(&colcnt[mg], 1);
                    Msh[q][w] = keep;
                }
            }
        }
        __syncthreads();  // B4

        // P5: recompute loop condition; reset has_conf
        if (tid < NG && colcnt[tid] == 0) flags[0] = 1;
        if (tid == 0) flags[1] = 0;
        __syncthreads();  // B5
    }

    // matched_qid: argmin_q of (M ? mutated cost : 1e30), exact mutated values
    for (int g = wave; g < NG; g += NWAVE) {
        int word = g >> 5;
        uint32_t bit = 1u << (g & 31);
        const float* col = costT + (size_t)g * NQ;
        float mv = INFINITY; int mi = 0x7fffffff;
        for (int q = lane; q < NQ; q += 64) {
            float v = 1e30f;
            if (Msh[q][word] & bit) {
                int c = cidx[q];
                v = (c >= 0) ? crow[c][g] : fmut(col[q], n_q[q]);
            }
            if (v < mv || (v == mv && q < mi)) { mv = v; mi = q; }
        }
        for (int off = 1; off < 64; off <<= 1) {
            float ov = __shfl_xor(mv, off); int oi = __shfl_xor(mi, off);
            if (ov < mv || (ov == mv && oi < mi)) { mv = ov; mi = oi; }
        }
        if (lane == 0) mqOut[g] = (float)mi;
    }
    // selected / gt_idx (overwrites rowamin region only after phase 3 reads: same block)
    for (int q = tid; q < NQ; q += BS) {
        uint4 m = *reinterpret_cast<const uint4*>(&Msh[q][0]);
        selOut[q] = (m.x | m.y | m.z | m.w) ? 1.0f : 0.0f;
        int gi = 0;
        if (m.x) gi = __ffs(m.x) - 1;
        else if (m.y) gi = 32 + __ffs(m.y) - 1;
        else if (m.z) gi = 64 + __ffs(m.z) - 1;
        else if (m.w) gi = 96 + __ffs(m.w) - 1;
        gtiOut[q] = (float)gi;
    }
    __syncthreads();  // all costT reads done before overwriting with M
    // M output (row-major q,g) overwrites costT buffer
    for (int i = tid; i < NQ * NG; i += BS) {
        int q = i / NG;
        int g = i - q * NG;
        costT[i] = (Msh[q][g >> 5] & (1u << (g & 31))) ? 1.0f : 0.0f;
    }
}

extern "C" void kernel_launch(void* const* d_in, const int* in_sizes, int n_in,
                              void* d_out, int out_size, void* d_ws, size_t ws_size,
                              hipStream_t stream) {
    const float* logits = (const float*)d_in[0];
    const float* pboxes = (const float*)d_in[1];
    const float* gboxes = (const float*)d_in[2];
    const int* labels = (const int*)d_in[3];
    const float* img = (const float*)d_in[4];
    float* out = (float*)d_out;
    float* lists = (float*)d_ws;  // BATCH*NG*6 floats = 38.4 KB

    // A1: fg_mask into selected-region (scratch; consumed by cost_kernel)
    fg_kernel<<<(BATCH * NQ + 255) / 256, 256, 0, stream>>>(pboxes, gboxes, img, out + OFF_SEL);
    // A2: transposed cost matrix into M-region
    cost_kernel<<<(BATCH * NQ * NG + 255) / 256, 256, 0, stream>>>(
        logits, pboxes, gboxes, labels, img, out + OFF_SEL, out + OFF_M);
    // A3: one wave per (b,g): dyn_k + bottom-5 cost indices
    dynk_init_kernel<<<BATCH * NG / 4, 256, 0, stream>>>(pboxes, gboxes, img, out + OFF_M, lists);
    // A4: per-row argmin of original cost (for conflict0 onehot)
    rowargmin_kernel<<<(BATCH * NQ + 255) / 256, 256, 0, stream>>>(out + OFF_M, out + OFF_GTI);
    // B: one block per batch
    match_kernel<<<BATCH, BS, 0, stream>>>(lists, out);
}